// Round 2
// baseline (240.966 us; speedup 1.0000x reference)
//
#include <hip/hip_runtime.h>
#include <math.h>

// ---------------- workspace layout (bytes) ----------------
// [0)            double sum
// [16)           unsigned minkey[64]
// [16+256)       unsigned maxkey[64]
// [16+512)       float u7[7]   (separable 1-D gaussian weights)

__device__ __forceinline__ unsigned fkey(float f) {
    unsigned u = __float_as_uint(f);
    return (u & 0x80000000u) ? ~u : (u | 0x80000000u);
}
__device__ __forceinline__ float funkey(unsigned k) {
    return __uint_as_float((k & 0x80000000u) ? (k & 0x7FFFFFFFu) : ~k);
}

__global__ void init_ws(const float* __restrict__ w, float* __restrict__ u7,
                        unsigned* __restrict__ mink, unsigned* __restrict__ maxk,
                        double* __restrict__ sum) {
    int t = threadIdx.x;
    if (t == 0) *sum = 0.0;
    if (t < 64) { mink[t] = 0xFFFFFFFFu; maxk[t] = 0u; }
    if (t < 7) {
        float s = 0.f;
        for (int j = 0; j < 7; ++j) s += w[t * 7 + j];
        u7[t] = s;  // row sums of normalized 2-D window == 1-D weights
    }
}

// per-batch min/max of Y. 16 blocks per batch, 256 threads, float4 loads.
__global__ __launch_bounds__(256) void minmax_kernel(const float4* __restrict__ Y,
                                                     unsigned* __restrict__ mink,
                                                     unsigned* __restrict__ maxk) {
    int b = blockIdx.x >> 4, ch = blockIdx.x & 15;
    const float4* p = Y + (size_t)b * 65536 + (size_t)ch * 4096 + threadIdx.x;
    float lmin = INFINITY, lmax = -INFINITY;
#pragma unroll
    for (int i = 0; i < 16; ++i) {
        float4 v = p[(size_t)i * 256];
        lmin = fminf(lmin, fminf(fminf(v.x, v.y), fminf(v.z, v.w)));
        lmax = fmaxf(lmax, fmaxf(fmaxf(v.x, v.y), fmaxf(v.z, v.w)));
    }
#pragma unroll
    for (int off = 32; off; off >>= 1) {
        lmin = fminf(lmin, __shfl_down(lmin, off));
        lmax = fmaxf(lmax, __shfl_down(lmax, off));
    }
    if ((threadIdx.x & 63) == 0) {
        atomicMin(&mink[b], fkey(lmin));
        atomicMax(&maxk[b], fkey(lmax));
    }
}

// Main SSIM kernel.
// Tile: 256 cols x 32 output rows. Grid = 64 images * 2 colstrips * 16 rowstrips = 2048.
// Separable blur. Vertical 7-deep register pipeline with STATIC slot indices:
// prologue fills 6 rows, then groups of 7 rows -> pipeline phase at group start
// is always 6 (mod 7), so (6+jj)%7 and (jj+k)%7 are compile-time constants in
// the unrolled jj-loop. No register shifts, 2 barriers per 7 rows.
__global__ __launch_bounds__(256, 6) void ssim_kernel(const float* __restrict__ X,
                                                      const float* __restrict__ Yg,
                                                      const float* __restrict__ u7,
                                                      const unsigned* __restrict__ mink,
                                                      const unsigned* __restrict__ maxk,
                                                      double* __restrict__ sum) {
    __shared__ float2 s[7][264];   // interleaved {x,y} rows, ds_read_b64 taps
    __shared__ float warpsum[4];

    const int blk = blockIdx.x;
    const int b   = blk >> 5;      // image
    const int sub = blk & 31;
    const int cs  = sub & 1;       // col strip (0..1)
    const int rs  = sub >> 1;      // row strip (0..15)
    const int c0  = cs * 256;
    const int r0  = rs * 32;
    const int t   = threadIdx.x;

    float u[7];
#pragma unroll
    for (int i = 0; i < 7; ++i) u[i] = u7[i];

    const float dr = funkey(maxk[b]) - funkey(mink[b]);
    float C1 = 0.01f * dr; C1 *= C1;
    float C2 = 0.03f * dr; C2 *= C2;
    const float cn = 49.f / 48.f;

    const float* __restrict__ Xb = X  + (size_t)b * 262144;
    const float* __restrict__ Yb = Yg + (size_t)b * 262144;

    // per-thread column setup (hoisted out of all row loops)
    const int  c1   = c0 - 3 + t;
    const int  cc1  = min(max(c1, 0), 511);
    const bool cok1 = (c1 >= 0) && (c1 < 512);
    const bool tail = (t < 6);
    const int  c2   = c0 + 253 + t;          // 256 + t - 3
    const int  cc2  = min(c2, 511);
    const bool cok2 = (c2 < 512);            // c2 >= 253 always >= 0

    // vertical register pipelines (slot = input_row_index mod 7, static)
    float phx[7], phy[7], phxx[7], phyy[7], phxy[7];

    float ssacc = 0.f;

    auto load_row = [&](int j, int slot) {   // j: row index relative to r0-3
        int  r   = r0 - 3 + j;
        bool rok = (r >= 0) && (r < 512);
        int  rr  = min(max(r, 0), 511);
        const float* xp = Xb + (size_t)rr * 512;
        const float* yp = Yb + (size_t)rr * 512;
        float xv = xp[cc1], yv = yp[cc1];
        bool ok = rok && cok1;
        s[slot][t] = make_float2(ok ? xv : 0.f, ok ? yv : 0.f);
        if (tail) {
            float xv2 = xp[cc2], yv2 = yp[cc2];
            bool ok2 = rok && cok2;
            s[slot][256 + t] = make_float2(ok2 ? xv2 : 0.f, ok2 ? yv2 : 0.f);
        }
    };

    auto hblur = [&](int bufslot, int pslot) {  // both compile-time constants
        float hx = 0.f, hy = 0.f, hxx = 0.f, hyy = 0.f, hxy = 0.f;
#pragma unroll
        for (int k = 0; k < 7; ++k) {
            float2 v = s[bufslot][t + k];
            float wx = u[k] * v.x;
            float wy = u[k] * v.y;
            hx += wx; hy += wy;
            hxx = fmaf(wx, v.x, hxx);
            hxy = fmaf(wx, v.y, hxy);
            hyy = fmaf(wy, v.y, hyy);
        }
        phx[pslot] = hx; phy[pslot] = hy;
        phxx[pslot] = hxx; phyy[pslot] = hyy; phxy[pslot] = hxy;
    };

    auto emit = [&](int jj) {   // jj compile-time constant 0..6
        hblur(jj, (6 + jj) % 7);
        float mux = 0.f, muy = 0.f, mxx = 0.f, myy = 0.f, mxy = 0.f;
#pragma unroll
        for (int k = 0; k < 7; ++k) {
            const int sl = (jj + k) % 7;
            mux = fmaf(u[k], phx[sl], mux);
            muy = fmaf(u[k], phy[sl], muy);
            mxx = fmaf(u[k], phxx[sl], mxx);
            myy = fmaf(u[k], phyy[sl], myy);
            mxy = fmaf(u[k], phxy[sl], mxy);
        }
        float mux2 = mux * mux, muy2 = muy * muy, muxy = mux * muy;
        float sxx = (mxx - mux2) * cn;
        float syy = (myy - muy2) * cn;
        float sxy = (mxy - muxy) * cn;
        float num = (2.f * muxy + C1) * (2.f * sxy + C2);
        float den = (mux2 + muy2 + C1) * (sxx + syy + C2);
        ssacc = fmaf(num, __builtin_amdgcn_rcpf(den), ssacc);
    };

    // prologue: input rows j=0..5 fill pipeline slots 0..5
#pragma unroll
    for (int j = 0; j < 6; ++j) load_row(j, j);
    __syncthreads();
#pragma unroll
    for (int j = 0; j < 6; ++j) hblur(j, j);
    __syncthreads();

    // 4 groups of 7 input rows -> outputs 0..27
    for (int g = 0; g < 4; ++g) {
        const int jbase = 6 + 7 * g;
#pragma unroll
        for (int jj = 0; jj < 7; ++jj) load_row(jbase + jj, jj);
        __syncthreads();
#pragma unroll
        for (int jj = 0; jj < 7; ++jj) emit(jj);
        __syncthreads();
    }
    // remainder: input rows 34..37 -> outputs 28..31 (same phase pattern)
#pragma unroll
    for (int jj = 0; jj < 4; ++jj) load_row(34 + jj, jj);
    __syncthreads();
#pragma unroll
    for (int jj = 0; jj < 4; ++jj) emit(jj);

    // block reduction: wave shuffle -> LDS -> one double atomic per block
#pragma unroll
    for (int off = 32; off; off >>= 1) ssacc += __shfl_down(ssacc, off);
    if ((t & 63) == 0) warpsum[t >> 6] = ssacc;
    __syncthreads();
    if (t == 0) {
        double sm = (double)warpsum[0] + (double)warpsum[1] +
                    (double)warpsum[2] + (double)warpsum[3];
        atomicAdd(sum, sm);
    }
}

__global__ void finalize_kernel(const double* __restrict__ sum, float* __restrict__ out) {
    out[0] = (float)(1.0 - (*sum) / (64.0 * 512.0 * 512.0));
}

extern "C" void kernel_launch(void* const* d_in, const int* in_sizes, int n_in,
                              void* d_out, int out_size, void* d_ws, size_t ws_size,
                              hipStream_t stream) {
    const float* X = (const float*)d_in[0];
    const float* Y = (const float*)d_in[1];
    const float* W = (const float*)d_in[2];

    char* ws = (char*)d_ws;
    double* sum = (double*)(ws + 0);
    unsigned* mink = (unsigned*)(ws + 16);
    unsigned* maxk = (unsigned*)(ws + 16 + 256);
    float* u7 = (float*)(ws + 16 + 512);

    init_ws<<<1, 64, 0, stream>>>(W, u7, mink, maxk, sum);
    minmax_kernel<<<1024, 256, 0, stream>>>((const float4*)Y, mink, maxk);
    ssim_kernel<<<2048, 256, 0, stream>>>(X, Y, u7, mink, maxk, sum);
    finalize_kernel<<<1, 1, 0, stream>>>(sum, (float*)d_out);
}

// Round 3
// 125.607 us; speedup vs baseline: 1.9184x; 1.9184x over previous
//
#include <hip/hip_runtime.h>
#include <math.h>

// ---------------- workspace layout (bytes) ----------------
// [0)            double sum
// [16)           unsigned minkey[64]
// [16+256)       unsigned maxkey[64]
// [16+512)       float u7[7]   (separable 1-D gaussian weights)

__device__ __forceinline__ unsigned fkey(float f) {
    unsigned u = __float_as_uint(f);
    return (u & 0x80000000u) ? ~u : (u | 0x80000000u);
}
__device__ __forceinline__ float funkey(unsigned k) {
    return __uint_as_float((k & 0x80000000u) ? (k & 0x7FFFFFFFu) : ~k);
}

__global__ void init_ws(const float* __restrict__ w, float* __restrict__ u7,
                        unsigned* __restrict__ mink, unsigned* __restrict__ maxk,
                        double* __restrict__ sum) {
    int t = threadIdx.x;
    if (t == 0) *sum = 0.0;
    if (t < 64) { mink[t] = 0xFFFFFFFFu; maxk[t] = 0u; }
    if (t < 7) {
        float s = 0.f;
        for (int j = 0; j < 7; ++j) s += w[t * 7 + j];
        u7[t] = s;  // row sums of normalized 2-D window == 1-D weights
    }
}

// per-batch min/max of Y. 16 blocks per batch, 256 threads, float4 loads.
__global__ __launch_bounds__(256) void minmax_kernel(const float4* __restrict__ Y,
                                                     unsigned* __restrict__ mink,
                                                     unsigned* __restrict__ maxk) {
    int b = blockIdx.x >> 4, ch = blockIdx.x & 15;
    const float4* p = Y + (size_t)b * 65536 + (size_t)ch * 4096 + threadIdx.x;
    float lmin = INFINITY, lmax = -INFINITY;
#pragma unroll
    for (int i = 0; i < 16; ++i) {
        float4 v = p[(size_t)i * 256];
        lmin = fminf(lmin, fminf(fminf(v.x, v.y), fminf(v.z, v.w)));
        lmax = fmaxf(lmax, fmaxf(fmaxf(v.x, v.y), fmaxf(v.z, v.w)));
    }
#pragma unroll
    for (int off = 32; off; off >>= 1) {
        lmin = fminf(lmin, __shfl_down(lmin, off));
        lmax = fmaxf(lmax, __shfl_down(lmax, off));
    }
    if ((threadIdx.x & 63) == 0) {
        atomicMin(&mink[b], fkey(lmin));
        atomicMax(&maxk[b], fkey(lmax));
    }
}

// Main SSIM kernel — round-1 structure (shift-register pipeline, proven to stay
// in VGPRs at 56 regs / zero scratch), with: 32-row tiles (2x grid), float2
// interleaved LDS rows (ds_read_b64 taps), rcp instead of divide, hoisted
// column bounds. Tile: 256 cols x 32 rows. Grid = 64 * 2 * 16 = 2048 blocks.
__global__ __launch_bounds__(256, 8) void ssim_kernel(const float* __restrict__ X,
                                                      const float* __restrict__ Yg,
                                                      const float* __restrict__ u7,
                                                      const unsigned* __restrict__ mink,
                                                      const unsigned* __restrict__ maxk,
                                                      double* __restrict__ sum) {
    __shared__ float2 s[2][264];   // double-buffered interleaved {x,y} row
    __shared__ float warpsum[4];

    const int blk = blockIdx.x;
    const int b   = blk >> 5;      // image
    const int sub = blk & 31;
    const int cs  = sub & 1;       // col strip (0..1)
    const int rs  = sub >> 1;      // row strip (0..15)
    const int c0  = cs * 256;
    const int r0  = rs * 32;
    const int t   = threadIdx.x;

    float u[7];
#pragma unroll
    for (int i = 0; i < 7; ++i) u[i] = u7[i];

    const float dr = funkey(maxk[b]) - funkey(mink[b]);
    float C1 = 0.01f * dr; C1 *= C1;
    float C2 = 0.03f * dr; C2 *= C2;
    const float cn = 49.f / 48.f;

    const float* __restrict__ Xb = X  + (size_t)b * 262144;
    const float* __restrict__ Yb = Yg + (size_t)b * 262144;

    // hoisted per-thread column setup
    const int  c1   = c0 - 3 + t;
    const int  cc1  = min(max(c1, 0), 511);
    const bool cok1 = (c1 >= 0) && (c1 < 512);
    const bool tail = (t < 6);
    const int  c2   = c0 + 253 + t;          // 256 + t - 3, always >= 253
    const int  cc2  = min(c2, 511);
    const bool cok2 = (c2 < 512);

    // vertical register pipelines (shift-register, static indices after unroll)
    float px[7], py[7], pxx[7], pyy[7], pxy[7];
#pragma unroll
    for (int k = 0; k < 7; ++k) { px[k]=0.f; py[k]=0.f; pxx[k]=0.f; pyy[k]=0.f; pxy[k]=0.f; }

    float ssacc = 0.f;

    auto load_row = [&](int j, int p) {      // input row r0-3+j -> buffer p
        int  r   = r0 - 3 + j;
        bool rok = (r >= 0) && (r < 512);
        int  rr  = min(max(r, 0), 511);
        const float* xp = Xb + (size_t)rr * 512;
        const float* yp = Yb + (size_t)rr * 512;
        float xv = xp[cc1], yv = yp[cc1];
        bool ok = rok && cok1;
        s[p][t] = make_float2(ok ? xv : 0.f, ok ? yv : 0.f);
        if (tail) {
            float xv2 = xp[cc2], yv2 = yp[cc2];
            bool ok2 = rok && cok2;
            s[p][256 + t] = make_float2(ok2 ? xv2 : 0.f, ok2 ? yv2 : 0.f);
        }
    };

    load_row(0, 0);
    __syncthreads();

    for (int j = 0; j < 38; ++j) {
        const int p = j & 1;
        if (j < 37) load_row(j + 1, p ^ 1);

        // horizontal blur of x, y, x^2, y^2, xy at input row r0-3+j
        float hx = 0.f, hy = 0.f, hxx = 0.f, hyy = 0.f, hxy = 0.f;
#pragma unroll
        for (int k = 0; k < 7; ++k) {
            float2 v = s[p][t + k];
            float wx = u[k] * v.x;
            float wy = u[k] * v.y;
            hx += wx; hy += wy;
            hxx = fmaf(wx, v.x, hxx);
            hxy = fmaf(wx, v.y, hxy);
            hyy = fmaf(wy, v.y, hyy);
        }

        // shift pipeline (stays in VGPRs: proven in round 1)
#pragma unroll
        for (int k = 0; k < 6; ++k) {
            px[k] = px[k + 1]; py[k] = py[k + 1];
            pxx[k] = pxx[k + 1]; pyy[k] = pyy[k + 1]; pxy[k] = pxy[k + 1];
        }
        px[6] = hx; py[6] = hy; pxx[6] = hxx; pyy[6] = hyy; pxy[6] = hxy;

        if (j >= 6) {
            float mux = 0.f, muy = 0.f, mxx = 0.f, myy = 0.f, mxy = 0.f;
#pragma unroll
            for (int k = 0; k < 7; ++k) {
                mux = fmaf(u[k], px[k], mux);
                muy = fmaf(u[k], py[k], muy);
                mxx = fmaf(u[k], pxx[k], mxx);
                myy = fmaf(u[k], pyy[k], myy);
                mxy = fmaf(u[k], pxy[k], mxy);
            }
            float mux2 = mux * mux, muy2 = muy * muy, muxy = mux * muy;
            float sxx = (mxx - mux2) * cn;
            float syy = (myy - muy2) * cn;
            float sxy = (mxy - muxy) * cn;
            float num = (2.f * muxy + C1) * (2.f * sxy + C2);
            float den = (mux2 + muy2 + C1) * (sxx + syy + C2);
            ssacc = fmaf(num, __builtin_amdgcn_rcpf(den), ssacc);
        }
        __syncthreads();
    }

    // block reduction: wave shuffle -> LDS -> one double atomic per block
#pragma unroll
    for (int off = 32; off; off >>= 1) ssacc += __shfl_down(ssacc, off);
    if ((t & 63) == 0) warpsum[t >> 6] = ssacc;
    __syncthreads();
    if (t == 0) {
        double sm = (double)warpsum[0] + (double)warpsum[1] +
                    (double)warpsum[2] + (double)warpsum[3];
        atomicAdd(sum, sm);
    }
}

__global__ void finalize_kernel(const double* __restrict__ sum, float* __restrict__ out) {
    out[0] = (float)(1.0 - (*sum) / (64.0 * 512.0 * 512.0));
}

extern "C" void kernel_launch(void* const* d_in, const int* in_sizes, int n_in,
                              void* d_out, int out_size, void* d_ws, size_t ws_size,
                              hipStream_t stream) {
    const float* X = (const float*)d_in[0];
    const float* Y = (const float*)d_in[1];
    const float* W = (const float*)d_in[2];

    char* ws = (char*)d_ws;
    double* sum = (double*)(ws + 0);
    unsigned* mink = (unsigned*)(ws + 16);
    unsigned* maxk = (unsigned*)(ws + 16 + 256);
    float* u7 = (float*)(ws + 16 + 512);

    init_ws<<<1, 64, 0, stream>>>(W, u7, mink, maxk, sum);
    minmax_kernel<<<1024, 256, 0, stream>>>((const float4*)Y, mink, maxk);
    ssim_kernel<<<2048, 256, 0, stream>>>(X, Y, u7, mink, maxk, sum);
    finalize_kernel<<<1, 1, 0, stream>>>(sum, (float*)d_out);
}

// Round 4
// 93.629 us; speedup vs baseline: 2.5736x; 1.3415x over previous
//
#include <hip/hip_runtime.h>
#include <math.h>

// ---------------- workspace layout (bytes) ----------------
// [0)            double sum
// [16)           unsigned minkey[64]
// [16+256)       unsigned maxkey[64]
// [16+512)       float u7[7]   (separable 1-D gaussian weights)

__device__ __forceinline__ unsigned fkey(float f) {
    unsigned u = __float_as_uint(f);
    return (u & 0x80000000u) ? ~u : (u | 0x80000000u);
}
__device__ __forceinline__ float funkey(unsigned k) {
    return __uint_as_float((k & 0x80000000u) ? (k & 0x7FFFFFFFu) : ~k);
}

__global__ void init_ws(const float* __restrict__ w, float* __restrict__ u7,
                        unsigned* __restrict__ mink, unsigned* __restrict__ maxk,
                        double* __restrict__ sum) {
    int t = threadIdx.x;
    if (t == 0) *sum = 0.0;
    if (t < 64) { mink[t] = 0xFFFFFFFFu; maxk[t] = 0u; }
    if (t < 7) {
        float s = 0.f;
        for (int j = 0; j < 7; ++j) s += w[t * 7 + j];
        u7[t] = s;  // row sums of normalized 2-D window == 1-D weights
    }
}

// per-batch min/max of Y. 16 blocks per batch, 256 threads, float4 loads.
__global__ __launch_bounds__(256) void minmax_kernel(const float4* __restrict__ Y,
                                                     unsigned* __restrict__ mink,
                                                     unsigned* __restrict__ maxk) {
    int b = blockIdx.x >> 4, ch = blockIdx.x & 15;
    const float4* p = Y + (size_t)b * 65536 + (size_t)ch * 4096 + threadIdx.x;
    float lmin = INFINITY, lmax = -INFINITY;
#pragma unroll
    for (int i = 0; i < 16; ++i) {
        float4 v = p[(size_t)i * 256];
        lmin = fminf(lmin, fminf(fminf(v.x, v.y), fminf(v.z, v.w)));
        lmax = fmaxf(lmax, fmaxf(fmaxf(v.x, v.y), fmaxf(v.z, v.w)));
    }
#pragma unroll
    for (int off = 32; off; off >>= 1) {
        lmin = fminf(lmin, __shfl_down(lmin, off));
        lmax = fmaxf(lmax, __shfl_down(lmax, off));
    }
    if ((threadIdx.x & 63) == 0) {
        atomicMin(&mink[b], fkey(lmin));
        atomicMax(&maxk[b], fkey(lmax));
    }
}

// ---------------------------------------------------------------------------
// Main SSIM kernel. Tile: 256 cols x 32 rows, grid 2048 = 64 img * 2 cs * 16 rs.
// 38 input rows/tile (j = 0..37, image row = r0-3+j). Structural points:
//  * mod-7 register ring for the vertical pipeline, all slot indices are
//    frontend integer-constant-expressions (macro literals) -> no shift movs,
//    no scratch (rule #20 safe).
//  * T14 split staging: step J computes row J from LDS, ds_writes row J+1
//    (loaded ~2 steps ago, vmcnt cheap), then issues loads for row J+3.
//  * main loop = 2 iterations of 14 macro steps (14 = lcm(2,7) -> phases are
//    loop-invariant literals).
// ---------------------------------------------------------------------------
__global__ __launch_bounds__(256, 4) void ssim_kernel(const float* __restrict__ X,
                                                      const float* __restrict__ Yg,
                                                      const float* __restrict__ u7,
                                                      const unsigned* __restrict__ mink,
                                                      const unsigned* __restrict__ maxk,
                                                      double* __restrict__ sum) {
    __shared__ float2 s[2][264];   // L = col - c0 + 3, L in [0,261]
    __shared__ float warpsum[4];

    const int blk = blockIdx.x;
    const int b   = blk >> 5;
    const int sub = blk & 31;
    const int cs  = sub & 1;
    const int rs  = sub >> 1;
    const int c0  = cs << 8;
    const int r0  = rs << 5;
    const int t   = threadIdx.x;

    float u[7];
#pragma unroll
    for (int i = 0; i < 7; ++i) u[i] = u7[i];

    const float dr = funkey(maxk[b]) - funkey(mink[b]);
    float C1 = 0.01f * dr; C1 *= C1;
    float C2 = 0.03f * dr; C2 *= C2;
    const float cn = 49.f / 48.f;

    const float* __restrict__ Xb = X  + ((size_t)b << 18);
    const float* __restrict__ Yb = Yg + ((size_t)b << 18);

    const int  c    = c0 + t;                     // main col, always in-image
    const bool hasE = (t < 6);                    // halo slots: L 0..2, 259..261
    const int  eL   = (t < 3) ? t : (t + 256);
    const int  ecol = c0 + eL - 3;
    const bool eok  = (ecol >= 0) && (ecol < 512);
    const int  ec   = min(max(ecol, 0), 511);

    float pxr[2], pyr[2], pxe[2], pye[2];         // prefetch reg sets (by row parity)
    float phx[7], phy[7], phxx[7], phyy[7], phxy[7];  // mod-7 ring
    float ssacc = 0.f;

#define LOADROW(P, JJ) do {                                                   \
    int r_ = r0 - 3 + (JJ);                                                   \
    if (r_ >= 0 && r_ < 512) {                                                \
        const float* xp_ = Xb + ((size_t)r_ << 9);                            \
        const float* yp_ = Yb + ((size_t)r_ << 9);                            \
        pxr[(P)] = xp_[c]; pyr[(P)] = yp_[c];                                 \
        if (hasE) { pxe[(P)] = eok ? xp_[ec] : 0.f;                           \
                    pye[(P)] = eok ? yp_[ec] : 0.f; }                         \
    } else {                                                                  \
        pxr[(P)] = 0.f; pyr[(P)] = 0.f; pxe[(P)] = 0.f; pye[(P)] = 0.f;       \
    }                                                                         \
} while (0)

#define WRITEROW(P) do {                                                      \
    s[(P)][t + 3] = make_float2(pxr[(P)], pyr[(P)]);                          \
    if (hasE) s[(P)][eL] = make_float2(pxe[(P)], pye[(P)]);                   \
} while (0)

#define HBLUR(BUF, SLOT) do {                                                 \
    float hx_ = 0.f, hy_ = 0.f, hxx_ = 0.f, hyy_ = 0.f, hxy_ = 0.f;           \
    _Pragma("unroll")                                                         \
    for (int k_ = 0; k_ < 7; ++k_) {                                          \
        float2 v_ = s[(BUF)][t + k_];                                         \
        float wx_ = u[k_] * v_.x, wy_ = u[k_] * v_.y;                         \
        hx_ += wx_; hy_ += wy_;                                               \
        hxx_ = fmaf(wx_, v_.x, hxx_);                                         \
        hxy_ = fmaf(wx_, v_.y, hxy_);                                         \
        hyy_ = fmaf(wy_, v_.y, hyy_);                                         \
    }                                                                         \
    phx[(SLOT)] = hx_; phy[(SLOT)] = hy_;                                     \
    phxx[(SLOT)] = hxx_; phyy[(SLOT)] = hyy_; phxy[(SLOT)] = hxy_;            \
} while (0)

// vertical blur: output row o = J-6, tap k reads slot (J+1+k)%7 with weight u[k]
#define VS(a, J) fmaf(u[6], a[(J) % 7], fmaf(u[5], a[((J)+6) % 7],            \
               fmaf(u[4], a[((J)+5) % 7], fmaf(u[3], a[((J)+4) % 7],          \
               fmaf(u[2], a[((J)+3) % 7], fmaf(u[1], a[((J)+2) % 7],          \
               u[0] * a[((J)+1) % 7]))))))

#define EMIT(J) do {                                                          \
    float mux = VS(phx, (J)), muy = VS(phy, (J));                             \
    float mxx = VS(phxx, (J)), myy = VS(phyy, (J)), mxy = VS(phxy, (J));      \
    float mux2 = mux * mux, muy2 = muy * muy, muxy = mux * muy;               \
    float sxx = (mxx - mux2) * cn;                                            \
    float syy = (myy - muy2) * cn;                                            \
    float sxy = (mxy - muxy) * cn;                                            \
    float num = (2.f * muxy + C1) * (2.f * sxy + C2);                         \
    float den = (mux2 + muy2 + C1) * (sxx + syy + C2);                        \
    ssacc = fmaf(num, __builtin_amdgcn_rcpf(den), ssacc);                     \
} while (0)

// prologue step (no emit), J literal 0..5, absolute rows
#define PSTEP(J) do {                                                         \
    HBLUR((J) & 1, (J) % 7);                                                  \
    WRITEROW(((J) + 1) & 1);                                                  \
    LOADROW(((J) + 1) & 1, (J) + 3);                                          \
    __syncthreads();                                                          \
} while (0)

// main step: real row j = jb + J; slot/parity depend on J only (jb % 14 == 0)
#define MSTEP(J) do {                                                         \
    HBLUR((J) & 1, (J) % 7);                                                  \
    EMIT(J);                                                                  \
    WRITEROW(((J) + 1) & 1);                                                  \
    LOADROW(((J) + 1) & 1, jb + (J) + 3);                                     \
    __syncthreads();                                                          \
} while (0)

#define MSTEP_NL(J) do {  /* no load (tail) */                                \
    HBLUR((J) & 1, (J) % 7);                                                  \
    EMIT(J);                                                                  \
    WRITEROW(((J) + 1) & 1);                                                  \
    __syncthreads();                                                          \
} while (0)

#define MSTEP_END(J) do { /* last row: no write, no barrier */                \
    HBLUR((J) & 1, (J) % 7);                                                  \
    EMIT(J);                                                                  \
} while (0)

    // pre-prologue: rows 0,1,2 in flight; row 0 staged to buf0
    LOADROW(0, 0);
    LOADROW(1, 1);
    WRITEROW(0);
    LOADROW(0, 2);
    __syncthreads();

    // prologue: rows 0..5 fill ring slots 0..5 (no outputs)
    PSTEP(0); PSTEP(1); PSTEP(2); PSTEP(3); PSTEP(4); PSTEP(5);

    // main: real rows 6..33 (28 outputs), phases are literal J = 6..19
    for (int g = 0; g < 2; ++g) {
        const int jb = 14 * g;
        MSTEP(6);  MSTEP(7);  MSTEP(8);  MSTEP(9);  MSTEP(10); MSTEP(11); MSTEP(12);
        MSTEP(13); MSTEP(14); MSTEP(15); MSTEP(16); MSTEP(17); MSTEP(18); MSTEP(19);
    }

    // tail: real rows 34..37 (outputs 28..31); 34 = 28+6 so literals 6..9 work
    {
        const int jb = 28;
        MSTEP(6);        // row 34, loads row 37
        MSTEP_NL(7);     // row 35 (row 38 doesn't exist)
        MSTEP_NL(8);     // row 36, writes row 37
        MSTEP_END(9);    // row 37
    }

#undef LOADROW
#undef WRITEROW
#undef HBLUR
#undef VS
#undef EMIT
#undef PSTEP
#undef MSTEP
#undef MSTEP_NL
#undef MSTEP_END

    // block reduction: wave shuffle -> LDS -> one double atomic per block
#pragma unroll
    for (int off = 32; off; off >>= 1) ssacc += __shfl_down(ssacc, off);
    if ((t & 63) == 0) warpsum[t >> 6] = ssacc;
    __syncthreads();
    if (t == 0) {
        double sm = (double)warpsum[0] + (double)warpsum[1] +
                    (double)warpsum[2] + (double)warpsum[3];
        atomicAdd(sum, sm);
    }
}

__global__ void finalize_kernel(const double* __restrict__ sum, float* __restrict__ out) {
    out[0] = (float)(1.0 - (*sum) / (64.0 * 512.0 * 512.0));
}

extern "C" void kernel_launch(void* const* d_in, const int* in_sizes, int n_in,
                              void* d_out, int out_size, void* d_ws, size_t ws_size,
                              hipStream_t stream) {
    const float* X = (const float*)d_in[0];
    const float* Y = (const float*)d_in[1];
    const float* W = (const float*)d_in[2];

    char* ws = (char*)d_ws;
    double* sum = (double*)(ws + 0);
    unsigned* mink = (unsigned*)(ws + 16);
    unsigned* maxk = (unsigned*)(ws + 16 + 256);
    float* u7 = (float*)(ws + 16 + 512);

    init_ws<<<1, 64, 0, stream>>>(W, u7, mink, maxk, sum);
    minmax_kernel<<<1024, 256, 0, stream>>>((const float4*)Y, mink, maxk);
    ssim_kernel<<<2048, 256, 0, stream>>>(X, Y, u7, mink, maxk, sum);
    finalize_kernel<<<1, 1, 0, stream>>>(sum, (float*)d_out);
}